// Round 9
// baseline (272.167 us; speedup 1.0000x reference)
//
#include <hip/hip_runtime.h>
#include <hip/hip_bf16.h>
#include <type_traits>

// ResGatedGraphConv x3 + softmax.
// R9: dim-chunked gather with XCD-affine chunks. KQVS stored chunk-major
// ([k32|qv64|s32] x N per 32-dim chunk, 5 MB/chunk -> random-access QV part
// 2.56 MB fits one XCD's 4 MB L2; chunk = blockIdx&7 pins chunk<->XCD).
// ushort ELL indices. L3 keeps flat layout (softmax needs whole row).
// N=20000 nodes, E=320000 edges, dims 256 -> 256 -> 128 -> 64.

#define NN 20000
#define EE 320000
#define ELLW 64  // max degree slot; Poisson(16) => P(deg>64) ~ 1e-19

typedef _Float16 half8 __attribute__((ext_vector_type(8)));
typedef _Float16 half4 __attribute__((ext_vector_type(4)));
typedef _Float16 half2v __attribute__((ext_vector_type(2)));
typedef float f32x4 __attribute__((ext_vector_type(4)));

__device__ __forceinline__ _Float16 f2h(float f) { return (_Float16)f; }
__device__ __forceinline__ float fsigmoid_mul(float v, float x) {
    // v * sigmoid(x), approx rcp (v_rcp_f32, ~1e-7 rel err)
    return v * __builtin_amdgcn_rcpf(1.f + __expf(-x));
}

// ---------------------------------------------------------------------------
// Column permutation (baked into Wt so the GEMM writes final memory order).
// Layers 1-2 (chunked): p-space = C chunks of 128 cols: [k(32)|qv(64)|s(32)],
// qv interleaved in 4-dim groups [q4|v4]; chunk c covers dims [c*32,(c+1)*32).
// Layer 3 (flat): [k64 | qv interleaved DV=1 | s64] as before.
struct PrepArgs {
    const float* w[3][4];  // [layer][grp k,q,v,skip]
    const float* b[3][4];  // [layer][grp] (skip slot = conv bias)
    _Float16* wt[3];
    float* cb[3];
};

// K0: blocks [0,79) zero deg | block 79 i64 probe | [80,1744) weight prep |
// [1744,4244) fp32->fp16 cast of x.
__global__ __launch_bounds__(256) void setup_all_kernel(
    const int* __restrict__ ei, int* __restrict__ deg, int* __restrict__ flag,
    const float* __restrict__ x, _Float16* __restrict__ Xh, PrepArgs a) {
    const int b = blockIdx.x;
    const int tid = threadIdx.x;
    if (b < 79) {
        const int i = b * 256 + tid;
        if (i < NN) deg[i] = 0;
    } else if (b == 79) {
        // int64-vs-int32 edge_index probe: if data is int64 (values < 2^31),
        // every odd int32 word is 0 (see R0 notes).
        __shared__ int nz;
        if (tid == 0) nz = 0;
        __syncthreads();
        int c = 0;
        for (int t = tid; t < 1024; t += 256)
            if (ei[2 * t + 1] != 0) c = 1;
        if (c) atomicAdd(&nz, 1);
        __syncthreads();
        if (tid == 0) *flag = (nz == 0) ? 1 : 0;
    } else if (b < 1744) {
        const int idx = (b - 80) * 256 + tid;  // < 425984
        int layer, li, K, D;
        if (idx < 262144) {
            layer = 0; li = idx; K = 256; D = 256;
        } else if (idx < 393216) {
            layer = 1; li = idx - 262144; K = 256; D = 128;
        } else {
            layer = 2; li = idx - 393216; K = 128; D = 64;
        }
        const int p = li / K;
        const int k = li - p * K;
        int grp, dim;
        if (layer < 2) {
            const int c = p >> 7;
            const int local = p & 127;
            if (local < 32) {
                grp = 0; dim = c * 32 + local;
            } else if (local < 96) {
                const int t = local - 32;
                const int g8 = t >> 3, r = t & 7;
                grp = (r < 4) ? 1 : 2;
                dim = c * 32 + g8 * 4 + (r & 3);
            } else {
                grp = 3; dim = c * 32 + local - 96;
            }
        } else {
            if (p < 64) {
                grp = 0; dim = p;
            } else if (p < 192) {
                const int t = p - 64;
                grp = (t & 1) ? 2 : 1;
                dim = t >> 1;
            } else {
                grp = 3; dim = p - 192;
            }
        }
        a.wt[layer][(size_t)p * K + k] =
            f2h(a.w[layer][grp][(size_t)k * D + dim]);
        if (k == 0) a.cb[layer][p] = a.b[layer][grp][dim];
    } else {
        const int i = ((b - 1744) * 256 + tid) * 8;
        if (i < NN * 256) {
            const float4 f0 = *(const float4*)(x + i);
            const float4 f1 = *(const float4*)(x + i + 4);
            half8 h;
            h[0] = f2h(f0.x); h[1] = f2h(f0.y); h[2] = f2h(f0.z); h[3] = f2h(f0.w);
            h[4] = f2h(f1.x); h[5] = f2h(f1.y); h[6] = f2h(f1.z); h[7] = f2h(f1.w);
            *(half8*)(Xh + i) = h;
        }
    }
}

// ---------------------------------------------------------------------------
// fp16 MFMA GEMM tile: C = A[M,K] @ Bt[N,K]^T + catbias -> fp16 O.
// 128x128 tile, BK=32, double-buffered staging, one barrier per K-iter.
// Epilogue transposes each wave's 64x64 tile through a private 4KB LDS zone.
// CHUNKED: O is chunk-major [(p>>7)][row][128]; else flat O[row][N].
template <bool CHUNKED>
__device__ __forceinline__ void gemm_tile(
    int bm, int bn, const _Float16* __restrict__ A,
    const _Float16* __restrict__ Bt, const float* __restrict__ catbias,
    _Float16* __restrict__ O, int M, int K, int N) {
    __shared__ _Float16 As[2][4096];  // [buf][row*32+k], 16 KB
    __shared__ _Float16 Bs[2][4096];

    const int tid = threadIdx.x;
    const int wid = tid >> 6;
    const int lane = tid & 63;
    const int tile_m = bm * 128;
    const int tile_n = bn * 128;
    const int wm = (wid & 1) * 64;
    const int wn = (wid >> 1) * 64;

    const int st_row = (wid << 4) + (lane >> 2);
    const int st_kc = (lane & 3) << 3;

    auto stage = [&](int buf, int kt) {
#pragma unroll
        for (int j = 0; j < 2; ++j) {
            int ar = tile_m + j * 64 + st_row;
            ar = ar < M ? ar : M - 1;  // clamp (stores are guarded)
            const _Float16* ag = A + (size_t)ar * K + kt + st_kc;
            __builtin_amdgcn_global_load_lds(
                (const __attribute__((address_space(1))) unsigned int*)ag,
                (__attribute__((address_space(3))) unsigned int*)
                    &As[buf][j * 2048 + (wid << 9)],
                16, 0, 0);
            const int br = tile_n + j * 64 + st_row;
            const _Float16* bg = Bt + (size_t)br * K + kt + st_kc;
            __builtin_amdgcn_global_load_lds(
                (const __attribute__((address_space(1))) unsigned int*)bg,
                (__attribute__((address_space(3))) unsigned int*)
                    &Bs[buf][j * 2048 + (wid << 9)],
                16, 0, 0);
        }
    };

    stage(0, 0);

    f32x4 acc[4][4] = {};
    const int fr = lane & 15;
    const int fk = (lane >> 4) << 3;
    const int niter = K >> 5;

    for (int it = 0; it < niter; ++it) {
        __syncthreads();  // drains vmcnt -> buf it&1 staged; prev reads done
        if (it + 1 < niter) stage((it + 1) & 1, (it + 1) << 5);
        const _Float16* as = As[it & 1];
        const _Float16* bs = Bs[it & 1];
        half8 af[4], bf[4];
#pragma unroll
        for (int mi = 0; mi < 4; ++mi)
            af[mi] = *(const half8*)&as[(wm + mi * 16 + fr) * 32 + fk];
#pragma unroll
        for (int ni = 0; ni < 4; ++ni)
            bf[ni] = *(const half8*)&bs[(wn + ni * 16 + fr) * 32 + fk];
#pragma unroll
        for (int mi = 0; mi < 4; ++mi)
#pragma unroll
            for (int ni = 0; ni < 4; ++ni)
                acc[mi][ni] = __builtin_amdgcn_mfma_f32_16x16x32_f16(
                    af[mi], bf[ni], acc[mi][ni], 0, 0, 0);
    }
    __syncthreads();  // all ds_reads done before LDS zones are reused

    // epilogue: C/D layout col=lane&15, row=(lane>>4)*4+reg
    _Float16* zone = &As[0][0] + wid * 2048;  // private 4 KB
    const int cl = lane & 15;
    const int rq = (lane >> 4) << 2;
    const int col0 = tile_n + wn;
    const int r0 = tile_m + wm;

    _Float16* obase;
    int ostride;
    if constexpr (CHUNKED) {
        obase = O + (size_t)(col0 >> 7) * NN * 128 + (col0 & 127);
        ostride = 128;
    } else {
        obase = O + col0;
        ostride = N;
    }
#pragma unroll
    for (int mi = 0; mi < 4; ++mi) {
#pragma unroll
        for (int ni = 0; ni < 4; ++ni) {
            const float cb = catbias[col0 + ni * 16 + cl];
#pragma unroll
            for (int r = 0; r < 4; ++r)
                zone[(rq + r) * 72 + ni * 16 + cl] = f2h(acc[mi][ni][r] + cb);
        }
#pragma unroll
        for (int j = 0; j < 2; ++j) {
            const int rr = j * 8 + (lane >> 3);
            const int row = r0 + mi * 16 + rr;
            const half8 v = *(const half8*)&zone[rr * 72 + (lane & 7) * 8];
            if (row < M)
                *(half8*)&obase[(size_t)row * ostride + (lane & 7) * 8] = v;
        }
    }
}

template <bool CHUNKED>
__global__ __launch_bounds__(256) void gemm_kernel(
    const _Float16* __restrict__ A, const _Float16* __restrict__ Bt,
    const float* __restrict__ catbias, _Float16* __restrict__ O, int M, int K,
    int N, int mblocks) {
    gemm_tile<CHUNKED>(blockIdx.x % mblocks, blockIdx.x / mblocks, A, Bt,
                       catbias, O, M, K, N);
}

// K1: blocks [0,1256) = GEMM layer 1 (chunked); [1256,2506) = ELL fill.
__global__ __launch_bounds__(256) void gemm1_fill_kernel(
    const _Float16* __restrict__ A, const _Float16* __restrict__ Bt,
    const float* __restrict__ catbias, _Float16* __restrict__ O,
    const int* __restrict__ ei, const int* __restrict__ i64flag,
    int* __restrict__ deg, unsigned short* __restrict__ col) {
    if (blockIdx.x < 1256) {
        gemm_tile<true>(blockIdx.x % 157, blockIdx.x / 157, A, Bt, catbias, O,
                        NN, 256, 1024);
        return;
    }
    const int e = (blockIdx.x - 1256) * 256 + threadIdx.x;
    if (e >= EE) return;
    int src, dst;
    if (*i64flag) {
        const long long* p = (const long long*)ei;
        src = (int)p[e];
        dst = (int)p[EE + e];
    } else {
        src = ei[e];
        dst = ei[EE + e];
    }
    const int pos = atomicAdd(&deg[dst], 1);
    if (pos < ELLW) col[dst * ELLW + pos] = (unsigned short)src;
}

// ---------------------------------------------------------------------------
// Chunked gather: one wave handles (node, 32-dim chunk). Chunk slice is the
// contiguous 5 MB region KQVS + chunk*NN*128; its random-access QV part is
// 2.56 MB -> L2-resident per XCD (chunk pinned to XCD via blockIdx&7).
// Lane = (edge-subgroup g = lane>>3, dim-group j = lane&7, 4 dims each).
// Per load-slot: 8 edges x 32 dims. shfl_xor reduction over g at the end.
// Writes fp16 Hh[node][D] row-major (next GEMM's A).
template <int NCH>  // chunks per layer; D = NCH*32
__global__ __launch_bounds__(256) void gather_chunked_kernel(
    const int* __restrict__ deg, const unsigned short* __restrict__ col,
    const _Float16* __restrict__ KQVS, _Float16* __restrict__ Hh, int n) {
    const int b = blockIdx.x;
    int chunk, group;
    if constexpr (NCH == 8) {
        chunk = b & 7;
        group = b >> 3;
    } else {  // NCH == 4: each chunk served by 2 XCD slots
        const int slot = b & 7;
        chunk = slot & 3;
        group = ((b >> 3) << 1) | (slot >> 2);
    }
    const int wid = threadIdx.x >> 6;
    const int node = group * 4 + wid;
    if (node >= n) return;
    const int lane = threadIdx.x & 63;
    const int j = lane & 7;   // dim-group (4 dims)
    const int g = lane >> 3;  // edge-subgroup

    const _Float16* cbase = KQVS + (size_t)chunk * NN * 128;
    const _Float16* nb = cbase + (size_t)node * 128;

    int dg = deg[node];
    dg = dg < ELLW ? dg : ELLW;
    int idx = (int)col[node * ELLW + lane];  // ELL slot 'lane'
    if (lane >= dg) idx = node;              // safe self-alias, masked below

    float k[4], acc[4] = {0.f, 0.f, 0.f, 0.f};
    {
        const half4 u = *(const half4*)(nb + j * 4);
#pragma unroll
        for (int t = 0; t < 4; ++t) k[t] = (float)u[t];
    }

    auto qvacc = [&](half8 u) {
#pragma unroll
        for (int t = 0; t < 4; ++t)
            acc[t] += fsigmoid_mul((float)u[4 + t], k[t] + (float)u[t]);
    };
    auto qvload = [&](int e) {
        const int s = __shfl(idx, e, 64);
        return *(const half8*)(cbase + (size_t)s * 128 + 32 + j * 8);
    };

    // rounds of 8 edges (1/lane-subgroup), 1-deep prefetch
    const int R = (dg + 7) >> 3;
    int e = g;
    half8 u = qvload(e);
    for (int i = 1; i < R; ++i) {
        const int en = i * 8 + g;
        const half8 un = qvload(en);
        if (e < dg) qvacc(u);
        u = un;
        e = en;
    }
    if (R > 0 && e < dg) qvacc(u);

    // reduce over edge-subgroups (fold lanes differing in bits 3..5)
#pragma unroll
    for (int t = 0; t < 4; ++t) {
        acc[t] += __shfl_xor(acc[t], 8, 64);
        acc[t] += __shfl_xor(acc[t], 16, 64);
        acc[t] += __shfl_xor(acc[t], 32, 64);
    }

    if (g == 0) {
        const half4 s4 = *(const half4*)(nb + 96 + j * 4);  // skip
        half4 o;
#pragma unroll
        for (int t = 0; t < 4; ++t) o[t] = f2h((float)s4[t] + acc[t]);
        *(half4*)(Hh + (size_t)node * (NCH * 32) + chunk * 32 + j * 4) = o;
    }
}

// ---------------------------------------------------------------------------
// Flat gather for layer 3 (D=64, fp16 [K|QV|S] rows, stride 256), one
// wave/node, fused row-softmax -> fp32 out. (5 MB working set; softmax needs
// the whole row in one wave, so no chunking here.)
__global__ __launch_bounds__(256) void edge_gather3_kernel(
    const int* __restrict__ deg, const unsigned short* __restrict__ col,
    const _Float16* __restrict__ KQVS, float* __restrict__ out, int n) {
    const int node = blockIdx.x * 4 + (threadIdx.x >> 6);
    if (node >= n) return;
    const int lane = threadIdx.x & 63;

    int dg = deg[node];
    dg = dg < ELLW ? dg : ELLW;
    int idx = (int)col[node * ELLW + lane];
    if (lane >= dg) idx = node;

    const float k = (float)KQVS[(size_t)node * 256 + lane];
    float acc = 0.f;
    const _Float16* qvbase = KQVS + 64 + 2 * lane;

    for (int e = 0; e < dg; e += 8) {
        half2v u[8];
#pragma unroll
        for (int t = 0; t < 8; ++t) {
            const int s = __shfl(idx, e + t, 64);
            u[t] = *(const half2v*)(qvbase + (size_t)s * 256);
        }
        const int nb = dg - e;  // wave-uniform
#pragma unroll
        for (int t = 0; t < 8; ++t)
            if (t < nb) acc += fsigmoid_mul((float)u[t][1], k + (float)u[t][0]);
    }

    const float h = (float)KQVS[(size_t)node * 256 + 192 + lane] + acc;

    float m = h;
#pragma unroll
    for (int off = 32; off > 0; off >>= 1)
        m = fmaxf(m, __shfl_xor(m, off, 64));
    const float ex = __expf(h - m);
    float sm = ex;
#pragma unroll
    for (int off = 32; off > 0; off >>= 1) sm += __shfl_xor(sm, off, 64);
    out[(size_t)node * 64 + lane] = ex * __builtin_amdgcn_rcpf(sm);
}

// ---------------------------------------------------------------------------
extern "C" void kernel_launch(void* const* d_in, const int* in_sizes, int n_in,
                              void* d_out, int out_size, void* d_ws,
                              size_t ws_size, hipStream_t stream) {
    const float* x = (const float*)d_in[0];
    const int* ei = (const int*)d_in[1];

    char* w = (char*)d_ws;
    _Float16* Xh = (_Float16*)w;     w += (size_t)NN * 256 * 2;
    _Float16* KQVS = (_Float16*)w;   w += (size_t)NN * 1024 * 2;
    _Float16* H1h = (_Float16*)w;    w += (size_t)NN * 256 * 2;
    _Float16* H2h = (_Float16*)w;    w += (size_t)NN * 128 * 2;
    _Float16* Wt1 = (_Float16*)w;    w += (size_t)1024 * 256 * 2;
    _Float16* Wt2 = (_Float16*)w;    w += (size_t)512 * 256 * 2;
    _Float16* Wt3 = (_Float16*)w;    w += (size_t)256 * 128 * 2;
    float* cb1 = (float*)w;          w += 1024 * 4;
    float* cb2 = (float*)w;          w += 512 * 4;
    float* cb3 = (float*)w;          w += 256 * 4;
    int* i64flag = (int*)w;          w += 16;
    int* deg = (int*)w;              w += (size_t)NN * 4;
    unsigned short* ell = (unsigned short*)w;  w += (size_t)NN * ELLW * 2;

    const dim3 blk(256);

    PrepArgs pa;
    pa.w[0][0] = (const float*)d_in[2];  pa.b[0][0] = (const float*)d_in[3];
    pa.w[0][1] = (const float*)d_in[4];  pa.b[0][1] = (const float*)d_in[5];
    pa.w[0][2] = (const float*)d_in[6];  pa.b[0][2] = (const float*)d_in[7];
    pa.w[1][0] = (const float*)d_in[8];  pa.b[1][0] = (const float*)d_in[9];
    pa.w[1][1] = (const float*)d_in[10]; pa.b[1][1] = (const float*)d_in[11];
    pa.w[1][2] = (const float*)d_in[12]; pa.b[1][2] = (const float*)d_in[13];
    pa.w[2][0] = (const float*)d_in[14]; pa.b[2][0] = (const float*)d_in[15];
    pa.w[2][1] = (const float*)d_in[16]; pa.b[2][1] = (const float*)d_in[17];
    pa.w[2][2] = (const float*)d_in[18]; pa.b[2][2] = (const float*)d_in[19];
    pa.w[0][3] = (const float*)d_in[20]; pa.b[0][3] = (const float*)d_in[21];
    pa.w[1][3] = (const float*)d_in[22]; pa.b[1][3] = (const float*)d_in[23];
    pa.w[2][3] = (const float*)d_in[24]; pa.b[2][3] = (const float*)d_in[25];
    pa.wt[0] = Wt1; pa.wt[1] = Wt2; pa.wt[2] = Wt3;
    pa.cb[0] = cb1; pa.cb[1] = cb2; pa.cb[2] = cb3;

    // K0: zero deg | i64 probe | weight prep | input cast  (4244 blocks)
    setup_all_kernel<<<4244, blk, 0, stream>>>(ei, deg, i64flag, x, Xh, pa);

    // K1: GEMM layer-1 chunked (1256 blocks) || ELL fill (1250 blocks)
    gemm1_fill_kernel<<<2506, blk, 0, stream>>>(Xh, Wt1, cb1, KQVS, ei,
                                                i64flag, deg, ell);
    // gather 1: 8 chunks x 5000 node-groups
    gather_chunked_kernel<8><<<40000, blk, 0, stream>>>(deg, ell, KQVS, H1h,
                                                        NN);

    // ---- layer 2: 256 -> 128 (chunked output) ----
    gemm_kernel<true><<<157 * 4, blk, 0, stream>>>(H1h, Wt2, cb2, KQVS, NN,
                                                   256, 512, 157);
    // gather 2: 4 chunks x 2 slots x 2500 groups
    gather_chunked_kernel<4><<<20000, blk, 0, stream>>>(deg, ell, KQVS, H2h,
                                                        NN);

    // ---- layer 3: 128 -> 64 flat, softmax fused into gather ----
    gemm_kernel<false><<<157 * 2, blk, 0, stream>>>(H2h, Wt3, cb3, KQVS, NN,
                                                    128, 256, 157);
    edge_gather3_kernel<<<(NN + 3) / 4, blk, 0, stream>>>(deg, ell, KQVS,
                                                          (float*)d_out, NN);
}